// Round 3
// baseline (281.280 us; speedup 1.0000x reference)
//
#include <hip/hip_runtime.h>
#include <math.h>

// Problem constants (B=1 fixed by reference)
#define NP 9216          // S*S spatial positions
#define DC 256           // channels
#define DN (DC * NP)
#define NT 72            // 9216 / 128 tiles per dim
#define KCH (NP * 32)    // halves per k-chunk section of a plane

#define FEPS 2.220446049250313e-16f

typedef __attribute__((ext_vector_type(8))) _Float16 half8v;
typedef __attribute__((ext_vector_type(4))) float   float4v;

union HU { _Float16 h; unsigned short u; };
__device__ __forceinline__ unsigned short f2h(float f) { HU x; x.h = (_Float16)f; return x.u; }
__device__ __forceinline__ float h2f(unsigned short s) { HU x; x.u = s; return (float)x.h; }

// Plane layout (k-major): half index off(n,k) = (k>>5)*KCH + n*32 + (k&31)
// -> a 128-row x 32-half (K=32) tile is 8 KB CONTIGUOUS: ideal for
// global_load_lds staging (LDS layout == global layout, linear).
//
// Split (same scale): s' = v*inv*2^8; H = fp16(s'), R = fp16(s' - H).
// sim*2^16 = Hx.Hy + Hx.Ry + Rx.Hy (Rx.Ry dropped, ~2^-22 rel)
// -> three chained MFMAs, no VALU fixup (identical numerics to R2).
//
// R3: ksim is fabric-byte-bound (R0/R2: MfmaUtil pinned at 30% while VALU
// and occupancy varied; 2.65 GB/183us = 14.4 TB/s = same wall as R8's 13.9).
// Fragment-direct loads duplicate every byte 2x within a block (A shared by
// 2 waves, B by 2 waves). Stage A+B tiles in LDS once per block -> 1.33 GB.

// ---------------- Kernel 1: fused normalize + fp16 H/R split ----------------
__global__ __launch_bounds__(256) void kprep(
    const float* __restrict__ X, const float* __restrict__ Y,
    float* __restrict__ Xf_out,
    unsigned short* __restrict__ XH, unsigned short* __restrict__ XR,
    unsigned short* __restrict__ YH, unsigned short* __restrict__ YR,
    float* __restrict__ lacc)
{
    __shared__ float tile[64 * 257];   // (n, d) at n*257+d
    __shared__ float psum[4][64];
    __shared__ float invs[64];

    const int t = threadIdx.x;
    const bool isX = (blockIdx.y == 0);
    const float* src = isX ? X : Y;
    unsigned* hT = (unsigned*)(isX ? XH : YH);
    unsigned* rT = (unsigned*)(isX ? XR : YR);
    const int n0 = blockIdx.x * 64;

    if (blockIdx.x == 0 && blockIdx.y == 0 && t == 0) *lacc = 0.0f;

    const int lane = t & 63;
    const int w    = t >> 6;      // wave id -> owns d-range [w*64, w*64+64)

    #pragma unroll 8
    for (int i = 0; i < 64; ++i) {
        int d = w * 64 + i;
        tile[lane * 257 + d] = src[(size_t)d * NP + n0 + lane];
    }
    float s = 0.0f;
    #pragma unroll 8
    for (int i = 0; i < 64; ++i) {
        float v = tile[lane * 257 + w * 64 + i];
        s = fmaf(v, v, s);
    }
    psum[w][lane] = s;
    __syncthreads();
    if (t < 64) {
        float tot = psum[0][t] + psum[1][t] + psum[2][t] + psum[3][t];
        invs[t] = 1.0f / (sqrtf(tot) + FEPS);
    }
    __syncthreads();

    // plane writes, k-major layout; coalesced uints.
    for (int kt = 0; kt < 8; ++kt) {
        #pragma unroll
        for (int p = 0; p < 4; ++p) {
            int idx = p * 256 + t;
            int n = idx >> 4;          // 0..63
            int u = idx & 15;          // uint within chunk (2 halves)
            float inv = invs[n] * 256.0f;
            int d = kt * 32 + 2 * u;
            float s0 = tile[n * 257 + d] * inv;
            float s1 = tile[n * 257 + d + 1] * inv;
            unsigned short h0 = f2h(s0), h1 = f2h(s1);
            unsigned short r0 = f2h(s0 - h2f(h0));
            unsigned short r1 = f2h(s1 - h2f(h1));
            size_t uo = (size_t)kt * (NP * 16) + (size_t)(n0 + n) * 16 + u;
            hT[uo] = (unsigned)h0 | ((unsigned)h1 << 16);
            rT[uo] = (unsigned)r0 | ((unsigned)r1 << 16);
        }
    }

    // exact fp32 Xf output ([d][n], coalesced over n)
    if (isX) {
        const float inv = invs[lane];
        #pragma unroll 8
        for (int i = 0; i < 64; ++i) {
            int d = w * 64 + i;
            Xf_out[(size_t)d * NP + n0 + lane] = tile[lane * 257 + d] * inv;
        }
    }
}

// ---------------- Kernel 2: LDS-staged MFMA sim-GEMM + fused argmax ----------
// Per kt: stage 32 KB (A-H|A-R|B-H|B-R, each 8 KB linear) into the other
// buffer via global_load_lds dwordx4 (8 instrs/thread), then 16 ds_read_b128
// fragments + 48 chained MFMAs from the current buffer. One vmcnt drain +
// one barrier per kt, AFTER the MFMA block (932 cyc of DMA flight time).
// 64 KB LDS -> 2 blocks/CU co-resident cover each other's stalls.

__device__ __forceinline__ void stage32k(
    const char* gA, const char* gB, char* buf, int t)
{
    // parts: 0=A-H, 1=A-R, 2=B-H, 3=B-R; R plane sits +2*DN bytes after H.
    #pragma unroll
    for (int i = 0; i < 8; ++i) {
        const int part = i >> 1;                    // compile-time
        const int within = (i & 1) * 256 + t;       // 0..511 (16B segs)
        const char* g = (part & 2) ? gB : gA;
        const size_t goff = (size_t)(part & 1) * (2 * (size_t)DN) + (size_t)within * 16;
        __builtin_amdgcn_global_load_lds(
            (const __attribute__((address_space(1))) void*)(g + goff),
            (__attribute__((address_space(3))) void*)(buf + (size_t)(i * 256 + t) * 16),
            16, 0, 0);
    }
}

__global__ __launch_bounds__(256, 2) void ksim(
    const unsigned short* __restrict__ XH, const unsigned short* __restrict__ XR,
    const unsigned short* __restrict__ YH, const unsigned short* __restrict__ YR,
    float* __restrict__ pmax, int* __restrict__ pidx)
{
    __shared__ __align__(1024) char smem[65536];   // 2 x 32 KB k-tile buffers

    const int t = threadIdx.x;

    // ---- XCD-aware block swizzle: lid -> (tx,ty) tile coords ----
    const int lid = blockIdx.y * NT + blockIdx.x;
    const int xcd = lid & 7;
    const int r   = lid >> 3;              // 0..647 within region
    const int sq  = r / 36;                // 6x6 sub-square index (0..17)
    const int wi  = r - sq * 36;           // 0..35 within sub-square
    const int qx  = sq % 3, qy = sq / 3;   // 3x6 grid of sub-squares
    const int sx  = wi % 6,  sy = wi / 6;
    const int tx  = (xcd & 3) * 18 + qx * 6 + sx;   // 0..71
    const int ty  = (xcd >> 2) * 36 + qy * 6 + sy;  // 0..71

    const int n0 = tx * 128;
    const int m0 = ty * 128;

    const int L   = t & 63;
    const int wid = t >> 6;
    const int wnb = (wid >> 1) * 64;   // wave n-offset
    const int wmb = (wid & 1) * 64;    // wave m-offset (col half)
    const int lc  = L & 15;
    const int lq  = L >> 4;

    // global tile bases (H planes; R at +2*DN inside stage32k)
    const char* gA = (const char*)XH + 2 * ((size_t)n0 * 32);
    const char* gB = (const char*)YH + 2 * ((size_t)m0 * 32);
    const size_t ktstep = 2 * (size_t)KCH;

    // LDS fragment byte offsets (linear [row][64B] layout per 8 KB part)
    const int aoff = (wnb + lc) * 64 + lq * 16;
    const int boff = (wmb + lc) * 64 + lq * 16;

    float4v acc[4][4];
    #pragma unroll
    for (int i = 0; i < 4; ++i)
        #pragma unroll
        for (int j = 0; j < 4; ++j)
            acc[i][j] = (float4v){0.f, 0.f, 0.f, 0.f};

    stage32k(gA, gB, smem, t);
    __syncthreads();                   // drains vmcnt(0): tile 0 landed

    #pragma unroll 2
    for (int kt = 0; kt < 8; ++kt) {
        const char* cur = smem + (kt & 1) * 32768;

        if (kt < 7)
            stage32k(gA + (size_t)(kt + 1) * ktstep, gB + (size_t)(kt + 1) * ktstep,
                     smem + ((kt + 1) & 1) * 32768, t);

        half8v Ah[4], Ar[4], Bh[4], Br[4];
        #pragma unroll
        for (int i = 0; i < 4; ++i) {
            Ah[i] = *(const half8v*)(cur +         aoff + i * 1024);
            Ar[i] = *(const half8v*)(cur +  8192 + aoff + i * 1024);
            Bh[i] = *(const half8v*)(cur + 16384 + boff + i * 1024);
            Br[i] = *(const half8v*)(cur + 24576 + boff + i * 1024);
        }
        #pragma unroll
        for (int cb = 0; cb < 4; ++cb)
            #pragma unroll
            for (int rb = 0; rb < 4; ++rb) {
                float4v v = acc[rb][cb];
                v = __builtin_amdgcn_mfma_f32_16x16x32_f16(Ah[rb], Bh[cb], v, 0, 0, 0);
                v = __builtin_amdgcn_mfma_f32_16x16x32_f16(Ah[rb], Br[cb], v, 0, 0, 0);
                v = __builtin_amdgcn_mfma_f32_16x16x32_f16(Ar[rb], Bh[cb], v, 0, 0, 0);
                acc[rb][cb] = v;
            }

        __syncthreads();   // drains vmcnt (next tile staged) + lgkm; gates reuse
    }

    // ---- epilogue: per-row argmax over own col-half ----
    // C/D map: col=lane&15, row=lq*4+reg. Scale 2^16 is argmax-invariant.
    float* v2s = (float*)smem;             // LDS reuse (post-barrier)
    int*   i2s = (int*)(smem + 1024);

    float bv[16]; int bc[16];
    #pragma unroll
    for (int s = 0; s < 16; ++s) { bv[s] = -INFINITY; bc[s] = 0; }

    #pragma unroll
    for (int rb = 0; rb < 4; ++rb)
        #pragma unroll
        for (int cb = 0; cb < 4; ++cb) {   // cb ascending = col ascending
            const int col = m0 + wmb + cb * 16 + lc;
            #pragma unroll
            for (int r2 = 0; r2 < 4; ++r2) {
                float v = acc[rb][cb][r2];
                int s = rb * 4 + r2;
                if (v > bv[s]) { bv[s] = v; bc[s] = col; }
            }
        }

    // reduce across the 16 lc lanes (xor<16 stays in the quad-group)
    #pragma unroll
    for (int off = 1; off < 16; off <<= 1) {
        #pragma unroll
        for (int s = 0; s < 16; ++s) {
            float ov = __shfl_xor(bv[s], off, 64);
            int   oi = __shfl_xor(bc[s], off, 64);
            if (ov > bv[s] || (ov == bv[s] && oi < bc[s])) { bv[s] = ov; bc[s] = oi; }
        }
    }

    // combine the two column-halves via LDS -> one slot per tile.
    // half0 cols < half1 cols: strict '>' keeps half0 on ties (first-max).
    if (lc == 0) {
        const int half = wid & 1;
        #pragma unroll
        for (int rb = 0; rb < 4; ++rb)
            #pragma unroll
            for (int r2 = 0; r2 < 4; ++r2) {
                int rl = wnb + rb * 16 + lq * 4 + r2;
                v2s[half * 128 + rl] = bv[rb * 4 + r2];
                i2s[half * 128 + rl] = bc[rb * 4 + r2];
            }
    }
    __syncthreads();
    if (t < 128) {
        float va = v2s[t], vb = v2s[128 + t];
        int   ia = i2s[t], ib = i2s[128 + t];
        bool useB = vb > va;
        pmax[(size_t)ty * NP + n0 + t] = useB ? vb : va;
        pidx[(size_t)ty * NP + n0 + t] = useB ? ib : ia;
    }
}

// ---------------- Kernel 3: reduce 72 tile partials -> nn_idx -------------
__global__ __launch_bounds__(256) void kred(
    const float* __restrict__ pmax, const int* __restrict__ pidx,
    int* __restrict__ nn)
{
    __shared__ float cv[4][64];
    __shared__ int   ci[4][64];

    const int t = threadIdx.x;
    const int n = blockIdx.x * 64 + (t & 63);
    const int p = t >> 6;

    float b = -INFINITY;
    int bi = 0x7fffffff;
    #pragma unroll 6
    for (int c = p * 18; c < p * 18 + 18; ++c) {
        float v = pmax[(size_t)c * NP + n];
        int  id = pidx[(size_t)c * NP + n];
        if (v > b || (v == b && id < bi)) { b = v; bi = id; }
    }
    cv[p][t & 63] = b;
    ci[p][t & 63] = bi;
    __syncthreads();
    if (t < 64) {
        b = cv[0][t]; bi = ci[0][t];
        #pragma unroll
        for (int q = 1; q < 4; ++q) {
            float v = cv[q][t]; int id = ci[q][t];
            if (v > b || (v == b && id < bi)) { b = v; bi = id; }
        }
        nn[blockIdx.x * 64 + t] = bi;
    }
}

// ---------------- Kernel 4: gather Y_sel + fused MSE loss ----------------
// y = (H + R) * 2^-8 (H/R same scale; error ~2^-22 relative).
__global__ __launch_bounds__(256) void kgather(
    const unsigned short* __restrict__ YH, const unsigned short* __restrict__ YR,
    const int* __restrict__ nn,
    const float* __restrict__ Xf, float* __restrict__ Ysel,
    float* __restrict__ lacc)
{
    __shared__ float tile[64][65];
    __shared__ int   idxs[64];
    __shared__ float wsum[4];

    const int n0 = blockIdx.x * 64;
    const int d0 = blockIdx.y * 64;
    const int tid = threadIdx.x;

    if (tid < 64) idxs[tid] = nn[n0 + tid];
    __syncthreads();

    const int c  = tid & 63;
    const int r0 = tid >> 6;

    #pragma unroll
    for (int s = 0; s < 16; ++s) {
        int r = s * 4 + r0;
        int d = d0 + c;
        size_t off = (size_t)(d >> 5) * KCH + (size_t)idxs[r] * 32 + (d & 31);
        tile[r][c] = (h2f(YH[off]) + h2f(YR[off])) * (1.0f / 256.0f);
    }
    __syncthreads();

    float lsum = 0.0f;
    #pragma unroll
    for (int s = 0; s < 16; ++s) {
        int a = s * 4 + r0;
        int d = d0 + a;
        int n = n0 + c;
        float y = tile[c][a];          // stride-65: conflict-free
        float x = Xf[(size_t)d * NP + n];
        float diff = x - y;
        lsum = fmaf(diff, diff, lsum);
        Ysel[(size_t)d * NP + n] = y;  // coalesced over n
    }

    #pragma unroll
    for (int off = 32; off >= 1; off >>= 1)
        lsum += __shfl_xor(lsum, off, 64);
    if ((tid & 63) == 0) wsum[tid >> 6] = lsum;
    __syncthreads();
    if (tid == 0)
        atomicAdd(lacc, wsum[0] + wsum[1] + wsum[2] + wsum[3]);
}

// ---------------- Kernel 5: finalize loss ----------------
__global__ void kfin(const float* __restrict__ lacc, float* __restrict__ out)
{
    out[0] = lacc[0] * (1.0f / (float)DN);
}

extern "C" void kernel_launch(void* const* d_in, const int* in_sizes, int n_in,
                              void* d_out, int out_size, void* d_ws, size_t ws_size,
                              hipStream_t stream)
{
    const float* X = (const float*)d_in[0];   // X_features [1,256,96,96]
    const float* Y = (const float*)d_in[1];   // Y_features [1,256,96,96]
    // d_in[2], d_in[3] (images) are dead code in the reference — unused.

    float* out = (float*)d_out;
    float* Ysel_out = out + 1;          // output 1: Y_sel [1,D,N]
    float* Xf_out   = out + 1 + DN;     // output 2: Xf   [1,D,N]  (exact fp32)

    // Workspace (~24.3 MB). XH|XR and YH|YR MUST be contiguous pairs:
    // stage32k derives R = H + 2*DN bytes.
    unsigned short* XH = (unsigned short*)d_ws;   // DN halves each
    unsigned short* XR = XH + DN;
    unsigned short* YH = XR + DN;
    unsigned short* YR = YH + DN;
    float* pmax = (float*)(YR + DN);                // NT*NP
    int*   pidx = (int*)(pmax + (size_t)NT * NP);   // NT*NP
    int*   nn   = pidx + (size_t)NT * NP;           // NP
    float* lacc = (float*)(nn + NP);                // 1

    hipLaunchKernelGGL(kprep, dim3(NP / 64, 2), dim3(256), 0, stream,
                       X, Y, Xf_out, XH, XR, YH, YR, lacc);
    hipLaunchKernelGGL(ksim, dim3(NT, NT), dim3(256), 0, stream,
                       XH, XR, YH, YR, pmax, pidx);
    hipLaunchKernelGGL(kred, dim3(NP / 64), dim3(256), 0, stream,
                       pmax, pidx, nn);
    hipLaunchKernelGGL(kgather, dim3(NP / 64, DC / 64), dim3(256), 0, stream,
                       YH, YR, nn, Xf_out, Ysel_out, lacc);
    hipLaunchKernelGGL(kfin, dim3(1), dim3(1), 0, stream, lacc, out);
}